// Round 8
// baseline (57.169 us; speedup 1.0000x reference)
//
#include <hip/hip_runtime.h>
#include <math.h>

#define BDIM 256
#define TP   16
#define C_   64
#define O_   64
#define H_   128
#define W_   128
#define KK_  9
#define CKK  576
#define HW_  (H_ * W_)          // 16384
#define KKS  72                 // padded kk-block stride in shorts (144 B)
#define ROWS (KK_ * KKS)        // 648 shorts per pixel row (1296 B)
#define XTP  72                 // compact x-tile row pad (shorts)

#define XHWC_OFF     131072     // byte offset of x_hwc (fp32) in ws
typedef short short8 __attribute__((ext_vector_type(8)));
typedef float f32x4  __attribute__((ext_vector_type(4)));

__device__ __forceinline__ unsigned short f2bf(float f) {
    unsigned int u = __float_as_uint(f);
    u += 0x7FFFu + ((u >> 16) & 1u);          // RNE (inputs finite)
    return (unsigned short)(u >> 16);
}

// packed RNE: lo -> bits[15:0], hi -> bits[31:16]
__device__ __forceinline__ unsigned int pk2bf(float lo, float hi) {
    unsigned int r;
    asm("v_cvt_pk_bf16_f32 %0, %1, %2" : "=v"(r) : "v"(lo), "v"(hi));
    return r;
}

// ---------------- pre: fused {x NCHW->HWC fp32 transpose} + {weight pack} ----
// wB : [4 tiles][18 ksteps][64 lanes][8]  (w_reg)   36864 shorts @ wpack+0
// wO : [2 tiles][18 ksteps][64 lanes][8]  (w_off/w_mod, cols>=27 zero) @ +36864
// logical K order: k = kk*64 + c ; fragment: k = kstep*32 + (lane>>4)*8 + j
__global__ __launch_bounds__(BDIM) void dcn_pre(
    const float* __restrict__ x, float* __restrict__ xh,
    const float* __restrict__ w_off, const float* __restrict__ w_mod,
    const float* __restrict__ w_reg, unsigned short* __restrict__ wpack)
{
    __shared__ float tile[32][33];
    if (blockIdx.x >= 4096) {
        // ---- weight pack (216 blocks * 256 = 55296 threads)
        int i = (blockIdx.x - 4096) * BDIM + threadIdx.x;
        bool isB = i < 36864;
        int r = isB ? i : i - 36864;
        int j    = r & 7;
        int lane = (r >> 3) & 63;
        int t2   = r >> 9;
        int kstep = t2 % 18;
        int tilei = t2 / 18;
        int k  = kstep * 32 + (lane >> 4) * 8 + j;
        int c  = k & 63;
        int kk = k >> 6;
        int col = tilei * 16 + (lane & 15);
        float v;
        if (isB) {
            v = w_reg[(size_t)col * CKK + c * KK_ + kk];
        } else {
            if (col < 18)      v = w_off[(size_t)col * CKK + c * KK_ + kk];
            else if (col < 27) v = w_mod[(size_t)(col - 18) * CKK + c * KK_ + kk];
            else               v = 0.f;
        }
        wpack[i] = f2bf(v);
        return;
    }
    // ---- transpose one (b, y, 32w, 32c) tile -> fp32 HWC
    int wq = blockIdx.x & 3;           // W/32
    int cq = (blockIdx.x >> 2) & 1;    // C/32
    int by = blockIdx.x >> 3;          // b*H + y
    int b = by >> 7, y = by & 127;
    int w0 = wq * 32, c0 = cq * 32;
    int tw = threadIdx.x & 31, tc = threadIdx.x >> 5;
    const float* xp = x + (size_t)b * C_ * HW_ + (size_t)y * W_;
    #pragma unroll
    for (int k = 0; k < 4; ++k)
        tile[tc + k * 8][tw] = xp[(size_t)(c0 + tc + k * 8) * HW_ + w0 + tw];
    __syncthreads();
    float* op = xh + ((size_t)b * HW_ + (size_t)y * W_) * C_;
    #pragma unroll
    for (int k = 0; k < 4; ++k)
        op[(size_t)(w0 + tc + k * 8) * C_ + c0 + tw] = tile[tw][tc + k * 8];
}

// ---------------- main fused kernel (fp32 HWC, compact A-tile, XCD swizzle) ----
__global__ __launch_bounds__(BDIM, 6) void dcn_fused_hwc(
    const float* __restrict__ xh,
    const float* __restrict__ b_off,
    const float* __restrict__ b_mod,
    const unsigned short* __restrict__ wB,
    const unsigned short* __restrict__ wO,
    float* __restrict__ out)
{
    // samp_s also hosts: compact x-tile (54*72 shorts = [0..3888)) during A-B,
    // and offs/msk (floats at short-offset 4096..4960) during B-C.
    __shared__ __align__(16) unsigned short samp_s[TP * ROWS];  // 20736 B
    __shared__ __align__(16) float4 wtab[TP * KK_];             // 2304 B
    __shared__ ushort4        itab[TP * KK_];                   // 1152 B
    __shared__ unsigned short dsttab[TP * KK_];                 // 288 B

    float* offs = (float*)(samp_s + 4096);   // 288 floats
    float* msk  = offs + TP * 18;            // 144 floats

    const int t    = threadIdx.x;
    const int wave = t >> 6;
    const int lane = t & 63;
    // XCD-aware swizzle: consecutive logical tiles land on the SAME XCD
    // (nwg=4096, nwg%8==0 -> bijective). XCD k serves 512 consecutive tiles
    // = 64 contiguous ho rows (~2.2 MB x_hwc slice, L2-resident).
    const int blk  = ((blockIdx.x & 7) << 9) | (blockIdx.x >> 3);
    const int wo0  = (blk & 7) * TP;
    const int ho   = (blk >> 3) & 127;
    const int b    = blk >> 10;

    const float* xb = xh + (size_t)b * HW_ * C_;

    // ---- A: stage compact bf16 tile xt[row=ry*18+col][c]
    for (int u = t; u < 54 * 16; u += BDIM) {
        int row = u >> 4;
        int c4  = (u & 15) * 4;
        int ry  = row / 18;
        int col = row - ry * 18;
        int gy  = ho - 1 + ry;
        int gx  = wo0 - 1 + col;
        float4 v = make_float4(0.f, 0.f, 0.f, 0.f);
        if (gy >= 0 && gy < H_ && gx >= 0 && gx < W_)
            v = *(const float4*)&xb[(size_t)(gy * W_ + gx) * C_ + c4];
        *(uint2*)&samp_s[row * XTP + c4] = make_uint2(pk2bf(v.x, v.y), pk2bf(v.z, v.w));
    }
    __syncthreads();

    // ---- B: offset(18)+mask(9) conv via MFMA from the compact tile
    if (wave < 2) {
        f32x4 acc = {0.f, 0.f, 0.f, 0.f};
        const unsigned short* bp = wO + ((size_t)(wave * 18) * 64 + lane) * 8;
        const unsigned short* ap = samp_s + (lane & 15) * XTP + (lane >> 4) * 8;
        #pragma unroll
        for (int ks = 0; ks < 18; ++ks) {
            const int kk = ks >> 1, ky = kk / 3, kx = kk - ky * 3;
            short8 av = *(const short8*)&ap[(ky * 18 + kx) * XTP + (ks & 1) * 32];
            short8 bv = *(const short8*)bp;  bp += 512;
            acc = __builtin_amdgcn_mfma_f32_16x16x32_bf16(av, bv, acc, 0, 0, 0);
        }
        int oc   = wave * 16 + (lane & 15);
        int prow = (lane >> 4) * 4;
        if (oc < 18) {
            float bias = b_off[oc];
            #pragma unroll
            for (int r = 0; r < 4; ++r) offs[(prow + r) * 18 + oc] = acc[r] + bias;
        } else if (oc < 27) {
            int mc = oc - 18;
            float bias = b_mod[mc];
            #pragma unroll
            for (int r = 0; r < 4; ++r)
                msk[(prow + r) * KK_ + mc] = 2.f / (1.f + expf(-(acc[r] + bias)));
        }
    }
    __syncthreads();

    // ---- C: positions -> folded (valid x mask x bilinear) weights + clamped idx
    if (t < TP * KK_) {
        int p  = t / 9;
        int kk = t - p * 9;
        int ky = kk / 3, kx = kk - ky * 3;
        float dy = offs[p * 18 + 2 * kk];
        float dx = offs[p * 18 + 2 * kk + 1];
        float py = dy + (float)(ho - 1 + ky);
        float px = dx + (float)(wo0 + p - 1 + kx);
        float y0f = floorf(py), x0f = floorf(px);
        float wy = py - y0f,    wx = px - x0f;
        int y0 = (int)y0f, x0 = (int)x0f;
        int y1 = y0 + 1,   x1 = x0 + 1;
        float m = msk[p * KK_ + kk];
        float vy0 = (y0 >= 0 && y0 < H_) ? 1.f : 0.f;
        float vy1 = (y1 >= 0 && y1 < H_) ? 1.f : 0.f;
        float vx0 = (x0 >= 0 && x0 < W_) ? 1.f : 0.f;
        float vx1 = (x1 >= 0 && x1 < W_) ? 1.f : 0.f;
        float4 wt;
        wt.x = (1.f - wy) * (1.f - wx) * m * vy0 * vx0;
        wt.y = (1.f - wy) * wx * m * vy0 * vx1;
        wt.z = wy * (1.f - wx) * m * vy1 * vx0;
        wt.w = wy * wx * m * vy1 * vx1;
        int yc0 = min(max(y0, 0), H_ - 1), yc1 = min(max(y1, 0), H_ - 1);
        int xc0 = min(max(x0, 0), W_ - 1), xc1 = min(max(x1, 0), W_ - 1);
        wtab[t] = wt;
        itab[t] = make_ushort4((unsigned short)(yc0 * W_ + xc0),
                               (unsigned short)(yc0 * W_ + xc1),
                               (unsigned short)(yc1 * W_ + xc0),
                               (unsigned short)(yc1 * W_ + xc1));
        dsttab[t] = (unsigned short)(p * ROWS + kk * KKS);
    }
    __syncthreads();

    // ---- D: bilinear gather from fp32 HWC, 4 ch/lane, branchless (no prefetch)
    {
        const int c4 = (lane & 15) * 4;
        const int q  = lane >> 4;
        const float* base = xb + c4;
        #pragma unroll
        for (int it = 0; it < 9; ++it) {
            const int e = wave * 36 + it * 4 + q;
            float4  wt  = wtab[e];
            ushort4 ix  = itab[e];
            int     dst = dsttab[e];
            float4 v00 = *(const float4*)(base + ((size_t)ix.x << 6));
            float4 v01 = *(const float4*)(base + ((size_t)ix.y << 6));
            float4 v10 = *(const float4*)(base + ((size_t)ix.z << 6));
            float4 v11 = *(const float4*)(base + ((size_t)ix.w << 6));
            float s0 = v00.x * wt.x;
            s0 = fmaf(v01.x, wt.y, s0); s0 = fmaf(v10.x, wt.z, s0); s0 = fmaf(v11.x, wt.w, s0);
            float s1 = v00.y * wt.x;
            s1 = fmaf(v01.y, wt.y, s1); s1 = fmaf(v10.y, wt.z, s1); s1 = fmaf(v11.y, wt.w, s1);
            float s2 = v00.z * wt.x;
            s2 = fmaf(v01.z, wt.y, s2); s2 = fmaf(v10.z, wt.z, s2); s2 = fmaf(v11.z, wt.w, s2);
            float s3 = v00.w * wt.x;
            s3 = fmaf(v01.w, wt.y, s3); s3 = fmaf(v10.w, wt.z, s3); s3 = fmaf(v11.w, wt.w, s3);
            *(uint2*)&samp_s[dst + c4] = make_uint2(pk2bf(s0, s1), pk2bf(s2, s3));
        }
    }
    __syncthreads();

    // ---- E: out[p][o] via MFMA, wave w -> o-tile w
    {
        f32x4 acc = {0.f, 0.f, 0.f, 0.f};
        const unsigned short* bp = wB + ((size_t)(wave * 18) * 64 + lane) * 8;
        const int arow = (lane & 15) * ROWS + (lane >> 4) * 8;
        #pragma unroll
        for (int ks = 0; ks < 18; ++ks) {
            short8 av = *(const short8*)&samp_s[arow + (ks >> 1) * KKS + (ks & 1) * 32];
            short8 bv = *(const short8*)bp;  bp += 512;
            acc = __builtin_amdgcn_mfma_f32_16x16x32_bf16(av, bv, acc, 0, 0, 0);
        }
        int o    = wave * 16 + (lane & 15);
        int prow = (lane >> 4) * 4;
        float* ob = out + (size_t)b * O_ * HW_ + (size_t)o * HW_ + ho * W_ + wo0;
        #pragma unroll
        for (int r = 0; r < 4; ++r) ob[prow + r] = acc[r];
    }
}

extern "C" void kernel_launch(void* const* d_in, const int* in_sizes, int n_in,
                              void* d_out, int out_size, void* d_ws, size_t ws_size,
                              hipStream_t stream) {
    const float* x     = (const float*)d_in[0];
    const float* w_off = (const float*)d_in[1];
    const float* b_off = (const float*)d_in[2];
    const float* w_mod = (const float*)d_in[3];
    const float* b_mod = (const float*)d_in[4];
    const float* w_reg = (const float*)d_in[5];
    float* out = (float*)d_out;

    unsigned short* wpack = (unsigned short*)d_ws;
    float* x_hwc = (float*)((char*)d_ws + XHWC_OFF);

    dcn_pre<<<4096 + 216, BDIM, 0, stream>>>(x, x_hwc, w_off, w_mod, w_reg, wpack);
    dcn_fused_hwc<<<4 * 128 * 8, BDIM, 0, stream>>>(x_hwc, b_off, b_mod,
                                                    wpack, wpack + 36864, out);
}

// Round 9
// 54.701 us; speedup vs baseline: 1.0451x; 1.0451x over previous
//
#include <hip/hip_runtime.h>
#include <math.h>

#define BDIM 256
#define TP   32                 // output pixels per block (along W)
#define C_   64
#define O_   64
#define H_   128
#define W_   128
#define KK_  9
#define CKK  576
#define HW_  (H_ * W_)          // 16384
#define KKS  72                 // padded kk-block stride in shorts (144 B)
#define ROWS (KK_ * KKS)        // 648 shorts per pixel row (1296 B)
#define XTP  72                 // compact x-tile row pad (shorts)
#define XCOLS 34                // compact tile cols (TP + 2 halo)
#define NE   (TP * KK_)         // 288 gather entries

#define XHWC_OFF     131072     // byte offset of x_hwc (fp32) in ws
typedef short short8 __attribute__((ext_vector_type(8)));
typedef float f32x4  __attribute__((ext_vector_type(4)));

__device__ __forceinline__ unsigned short f2bf(float f) {
    unsigned int u = __float_as_uint(f);
    u += 0x7FFFu + ((u >> 16) & 1u);          // RNE (inputs finite)
    return (unsigned short)(u >> 16);
}

// packed RNE: lo -> bits[15:0], hi -> bits[31:16]
__device__ __forceinline__ unsigned int pk2bf(float lo, float hi) {
    unsigned int r;
    asm("v_cvt_pk_bf16_f32 %0, %1, %2" : "=v"(r) : "v"(lo), "v"(hi));
    return r;
}

// ---------------- pre: fused {x NCHW->HWC fp32 transpose} + {weight pack} ----
// wB : [4 tiles][18 ksteps][64 lanes][8]  (w_reg)   36864 shorts @ wpack+0
// wO : [2 tiles][18 ksteps][64 lanes][8]  (w_off/w_mod, cols>=27 zero) @ +36864
// logical K order: k = kk*64 + c ; fragment: k = kstep*32 + (lane>>4)*8 + j
__global__ __launch_bounds__(BDIM) void dcn_pre(
    const float* __restrict__ x, float* __restrict__ xh,
    const float* __restrict__ w_off, const float* __restrict__ w_mod,
    const float* __restrict__ w_reg, unsigned short* __restrict__ wpack)
{
    __shared__ float tile[32][33];
    if (blockIdx.x >= 4096) {
        // ---- weight pack (216 blocks * 256 = 55296 threads)
        int i = (blockIdx.x - 4096) * BDIM + threadIdx.x;
        bool isB = i < 36864;
        int r = isB ? i : i - 36864;
        int j    = r & 7;
        int lane = (r >> 3) & 63;
        int t2   = r >> 9;
        int kstep = t2 % 18;
        int tilei = t2 / 18;
        int k  = kstep * 32 + (lane >> 4) * 8 + j;
        int c  = k & 63;
        int kk = k >> 6;
        int col = tilei * 16 + (lane & 15);
        float v;
        if (isB) {
            v = w_reg[(size_t)col * CKK + c * KK_ + kk];
        } else {
            if (col < 18)      v = w_off[(size_t)col * CKK + c * KK_ + kk];
            else if (col < 27) v = w_mod[(size_t)(col - 18) * CKK + c * KK_ + kk];
            else               v = 0.f;
        }
        wpack[i] = f2bf(v);
        return;
    }
    // ---- transpose one (b, y, 32w, 32c) tile -> fp32 HWC
    int wq = blockIdx.x & 3;           // W/32
    int cq = (blockIdx.x >> 2) & 1;    // C/32
    int by = blockIdx.x >> 3;          // b*H + y
    int b = by >> 7, y = by & 127;
    int w0 = wq * 32, c0 = cq * 32;
    int tw = threadIdx.x & 31, tc = threadIdx.x >> 5;
    const float* xp = x + (size_t)b * C_ * HW_ + (size_t)y * W_;
    #pragma unroll
    for (int k = 0; k < 4; ++k)
        tile[tc + k * 8][tw] = xp[(size_t)(c0 + tc + k * 8) * HW_ + w0 + tw];
    __syncthreads();
    float* op = xh + ((size_t)b * HW_ + (size_t)y * W_) * C_;
    #pragma unroll
    for (int k = 0; k < 4; ++k)
        op[(size_t)(w0 + tc + k * 8) * C_ + c0 + tw] = tile[tw][tc + k * 8];
}

// ---------------- main fused kernel (TP=32, B-fragment reuse x2) ----------------
__global__ __launch_bounds__(BDIM, 3) void dcn_fused_hwc(
    const float* __restrict__ xh,
    const float* __restrict__ b_off,
    const float* __restrict__ b_mod,
    const unsigned short* __restrict__ wB,
    const unsigned short* __restrict__ wO,
    float* __restrict__ out)
{
    // samp_s also hosts: compact x-tile (102*72 shorts = [0..7344)) during A-B,
    // and offs/msk (floats at short-offset 8192..9920) during B-C.
    __shared__ __align__(16) unsigned short samp_s[TP * ROWS];  // 41472 B
    __shared__ __align__(16) float4 wtab[NE];                   // 4608 B
    __shared__ ushort4        itab[NE];                         // 2304 B
    __shared__ unsigned short dsttab[NE];                       // 576 B

    float* offs = (float*)(samp_s + 8192);   // 576 floats
    float* msk  = offs + TP * 18;            // 288 floats

    const int t    = threadIdx.x;
    const int wave = t >> 6;
    const int lane = t & 63;
    // XCD-aware swizzle (nwg=2048, %8==0 -> bijective): XCD k serves 256
    // consecutive logical tiles = 64 contiguous ho rows (~4.3 MB slice).
    const int blk  = ((blockIdx.x & 7) << 8) | (blockIdx.x >> 3);
    const int wo0  = (blk & 3) * TP;          // 4 tiles per row
    const int ho   = (blk >> 2) & 127;
    const int b    = blk >> 9;

    const float* xb = xh + (size_t)b * HW_ * C_;

    // ---- A: stage compact bf16 tile xt[row=ry*34+col][c], 102 rows x 64 ch
    for (int u = t; u < 102 * 16; u += BDIM) {
        int row = u >> 4;
        int c4  = (u & 15) * 4;
        int ry  = row / XCOLS;
        int col = row - ry * XCOLS;
        int gy  = ho - 1 + ry;
        int gx  = wo0 - 1 + col;
        float4 v = make_float4(0.f, 0.f, 0.f, 0.f);
        if (gy >= 0 && gy < H_ && gx >= 0 && gx < W_)
            v = *(const float4*)&xb[(size_t)(gy * W_ + gx) * C_ + c4];
        *(uint2*)&samp_s[row * XTP + c4] = make_uint2(pk2bf(v.x, v.y), pk2bf(v.z, v.w));
    }
    __syncthreads();

    // ---- B: offset(18)+mask(9) conv via MFMA; 1 bp load feeds 2 pixel halves
    if (wave < 2) {
        f32x4 acc0 = {0.f, 0.f, 0.f, 0.f};
        f32x4 acc1 = {0.f, 0.f, 0.f, 0.f};
        const unsigned short* bp = wO + ((size_t)(wave * 18) * 64 + lane) * 8;
        const unsigned short* ap = samp_s + (lane & 15) * XTP + (lane >> 4) * 8;
        #pragma unroll
        for (int ks = 0; ks < 18; ++ks) {
            const int kk = ks >> 1, ky = kk / 3, kx = kk - ky * 3;
            const int ro = (ky * XCOLS + kx) * XTP + (ks & 1) * 32;
            short8 av0 = *(const short8*)&ap[ro];
            short8 av1 = *(const short8*)&ap[ro + 16 * XTP];
            short8 bv  = *(const short8*)bp;  bp += 512;
            acc0 = __builtin_amdgcn_mfma_f32_16x16x32_bf16(av0, bv, acc0, 0, 0, 0);
            acc1 = __builtin_amdgcn_mfma_f32_16x16x32_bf16(av1, bv, acc1, 0, 0, 0);
        }
        int oc   = wave * 16 + (lane & 15);
        int prow = (lane >> 4) * 4;
        if (oc < 18) {
            float bias = b_off[oc];
            #pragma unroll
            for (int r = 0; r < 4; ++r) {
                offs[(prow + r) * 18 + oc]      = acc0[r] + bias;
                offs[(prow + 16 + r) * 18 + oc] = acc1[r] + bias;
            }
        } else if (oc < 27) {
            int mc = oc - 18;
            float bias = b_mod[mc];
            #pragma unroll
            for (int r = 0; r < 4; ++r) {
                msk[(prow + r) * KK_ + mc]      = 2.f / (1.f + expf(-(acc0[r] + bias)));
                msk[(prow + 16 + r) * KK_ + mc] = 2.f / (1.f + expf(-(acc1[r] + bias)));
            }
        }
    }
    __syncthreads();

    // ---- C: positions -> folded (valid x mask x bilinear) weights + clamped idx
    for (int e = t; e < NE; e += BDIM) {
        int p  = e / 9;
        int kk = e - p * 9;
        int ky = kk / 3, kx = kk - ky * 3;
        float dy = offs[p * 18 + 2 * kk];
        float dx = offs[p * 18 + 2 * kk + 1];
        float py = dy + (float)(ho - 1 + ky);
        float px = dx + (float)(wo0 + p - 1 + kx);
        float y0f = floorf(py), x0f = floorf(px);
        float wy = py - y0f,    wx = px - x0f;
        int y0 = (int)y0f, x0 = (int)x0f;
        int y1 = y0 + 1,   x1 = x0 + 1;
        float m = msk[p * KK_ + kk];
        float vy0 = (y0 >= 0 && y0 < H_) ? 1.f : 0.f;
        float vy1 = (y1 >= 0 && y1 < H_) ? 1.f : 0.f;
        float vx0 = (x0 >= 0 && x0 < W_) ? 1.f : 0.f;
        float vx1 = (x1 >= 0 && x1 < W_) ? 1.f : 0.f;
        float4 wt;
        wt.x = (1.f - wy) * (1.f - wx) * m * vy0 * vx0;
        wt.y = (1.f - wy) * wx * m * vy0 * vx1;
        wt.z = wy * (1.f - wx) * m * vy1 * vx0;
        wt.w = wy * wx * m * vy1 * vx1;
        int yc0 = min(max(y0, 0), H_ - 1), yc1 = min(max(y1, 0), H_ - 1);
        int xc0 = min(max(x0, 0), W_ - 1), xc1 = min(max(x1, 0), W_ - 1);
        wtab[e] = wt;
        itab[e] = make_ushort4((unsigned short)(yc0 * W_ + xc0),
                               (unsigned short)(yc0 * W_ + xc1),
                               (unsigned short)(yc1 * W_ + xc0),
                               (unsigned short)(yc1 * W_ + xc1));
        dsttab[e] = (unsigned short)(p * ROWS + kk * KKS);
    }
    __syncthreads();

    // ---- D: bilinear gather from fp32 HWC, 4 ch/lane, branchless
    {
        const int c4 = (lane & 15) * 4;
        const int q  = lane >> 4;
        const float* base = xb + c4;
        #pragma unroll
        for (int it = 0; it < 18; ++it) {
            const int e = wave * 72 + it * 4 + q;
            float4  wt  = wtab[e];
            ushort4 ix  = itab[e];
            int     dst = dsttab[e];
            float4 v00 = *(const float4*)(base + ((size_t)ix.x << 6));
            float4 v01 = *(const float4*)(base + ((size_t)ix.y << 6));
            float4 v10 = *(const float4*)(base + ((size_t)ix.z << 6));
            float4 v11 = *(const float4*)(base + ((size_t)ix.w << 6));
            float s0 = v00.x * wt.x;
            s0 = fmaf(v01.x, wt.y, s0); s0 = fmaf(v10.x, wt.z, s0); s0 = fmaf(v11.x, wt.w, s0);
            float s1 = v00.y * wt.x;
            s1 = fmaf(v01.y, wt.y, s1); s1 = fmaf(v10.y, wt.z, s1); s1 = fmaf(v11.y, wt.w, s1);
            float s2 = v00.z * wt.x;
            s2 = fmaf(v01.z, wt.y, s2); s2 = fmaf(v10.z, wt.z, s2); s2 = fmaf(v11.z, wt.w, s2);
            float s3 = v00.w * wt.x;
            s3 = fmaf(v01.w, wt.y, s3); s3 = fmaf(v10.w, wt.z, s3); s3 = fmaf(v11.w, wt.w, s3);
            *(uint2*)&samp_s[dst + c4] = make_uint2(pk2bf(s0, s1), pk2bf(s2, s3));
        }
    }
    __syncthreads();

    // ---- E: out[p][o] via MFMA; 1 bp load feeds 2 pixel halves
    {
        f32x4 acc0 = {0.f, 0.f, 0.f, 0.f};
        f32x4 acc1 = {0.f, 0.f, 0.f, 0.f};
        const unsigned short* bp = wB + ((size_t)(wave * 18) * 64 + lane) * 8;
        const int arow = (lane & 15) * ROWS + (lane >> 4) * 8;
        #pragma unroll
        for (int ks = 0; ks < 18; ++ks) {
            const int ro = arow + (ks >> 1) * KKS + (ks & 1) * 32;
            short8 av0 = *(const short8*)&samp_s[ro];
            short8 av1 = *(const short8*)&samp_s[ro + 16 * ROWS];
            short8 bv  = *(const short8*)bp;  bp += 512;
            acc0 = __builtin_amdgcn_mfma_f32_16x16x32_bf16(av0, bv, acc0, 0, 0, 0);
            acc1 = __builtin_amdgcn_mfma_f32_16x16x32_bf16(av1, bv, acc1, 0, 0, 0);
        }
        int o    = wave * 16 + (lane & 15);
        int prow = (lane >> 4) * 4;
        float* ob = out + (size_t)b * O_ * HW_ + (size_t)o * HW_ + ho * W_ + wo0;
        #pragma unroll
        for (int r = 0; r < 4; ++r) {
            ob[prow + r]      = acc0[r];
            ob[16 + prow + r] = acc1[r];
        }
    }
}

extern "C" void kernel_launch(void* const* d_in, const int* in_sizes, int n_in,
                              void* d_out, int out_size, void* d_ws, size_t ws_size,
                              hipStream_t stream) {
    const float* x     = (const float*)d_in[0];
    const float* w_off = (const float*)d_in[1];
    const float* b_off = (const float*)d_in[2];
    const float* w_mod = (const float*)d_in[3];
    const float* b_mod = (const float*)d_in[4];
    const float* w_reg = (const float*)d_in[5];
    float* out = (float*)d_out;

    unsigned short* wpack = (unsigned short*)d_ws;
    float* x_hwc = (float*)((char*)d_ws + XHWC_OFF);

    dcn_pre<<<4096 + 216, BDIM, 0, stream>>>(x, x_hwc, w_off, w_mod, w_reg, wpack);
    dcn_fused_hwc<<<4 * 128 * 4, BDIM, 0, stream>>>(x_hwc, b_off, b_mod,
                                                    wpack, wpack + 36864, out);
}